// Round 1
// baseline (221.420 us; speedup 1.0000x reference)
//
#include <hip/hip_runtime.h>

// SetCriterion loss (DETR-style) fused single-pass reduction.
// Inputs (float32 unless noted):
//   d_in[0] pred_logits  [B,T,N,14]  = [1.6M rows, 14]
//   d_in[1] pred_doa     [B,T,N,3]
//   d_in[2] target_doa   [B*T,N,3]
//   d_in[3] empty_weight [14]
//   d_in[4] target_classes (int32) [B*T,N]
// Output: scalar float32.

constexpr int   kC      = 14;    // NUM_CLASSES + 1
constexpr int   kNoObj  = 13;    // NUM_CLASSES
constexpr float kWClass = 1.0f;
constexpr float kWDoa   = 2.0f;
constexpr int   kBlock  = 256;
constexpr int   kMaxGrid = 2048;

struct Accum {
    double s_wce;               // sum of empty_weight[t] * CE
    double s_abs;               // sum of |pred - tgt| over matched rows
    unsigned long long cnt;     // # matched rows
};

__global__ void init_accum(Accum* ws) {
    if (threadIdx.x == 0 && blockIdx.x == 0) {
        ws->s_wce = 0.0;
        ws->s_abs = 0.0;
        ws->cnt   = 0ull;
    }
}

__global__ __launch_bounds__(kBlock) void loss_main(
    const float* __restrict__ logits,   // [R, 14]
    const float* __restrict__ pdoa,     // [R, 3]
    const float* __restrict__ tdoa,     // [R, 3]
    const float* __restrict__ ew,       // [14]
    const int*   __restrict__ tcls,     // [R]
    int npairs,                         // R/2 (R is even: 1,600,000)
    Accum* ws)
{
    float        s_wce = 0.f;
    float        s_abs = 0.f;
    unsigned int cnt   = 0u;

    const int stride = gridDim.x * blockDim.x;
    for (int p = blockIdx.x * blockDim.x + threadIdx.x; p < npairs; p += stride) {
        // ---- two logit rows: 28 floats = 112 B, 16B-aligned -> 7x dwordx4 ----
        const float4* lp = reinterpret_cast<const float4*>(logits + (size_t)p * (2 * kC));
        float x[2 * kC];
#pragma unroll
        for (int j = 0; j < 7; ++j) {
            float4 v = lp[j];
            x[4 * j + 0] = v.x;
            x[4 * j + 1] = v.y;
            x[4 * j + 2] = v.z;
            x[4 * j + 3] = v.w;
        }
        const int2 tc = *reinterpret_cast<const int2*>(tcls + (size_t)p * 2);

        // ---- DOA: 6 floats each side (2 rows x 3), 8B-aligned -> float2 ----
        const float2* pd = reinterpret_cast<const float2*>(pdoa + (size_t)p * 6);
        const float2* td = reinterpret_cast<const float2*>(tdoa + (size_t)p * 6);
        const float2 a0 = pd[0], a1 = pd[1], a2 = pd[2];
        const float2 b0 = td[0], b1 = td[1], b2 = td[2];

        // ---- weighted CE for the two rows ----
#pragma unroll
        for (int r = 0; r < 2; ++r) {
            const int base = r * kC;          // compile-time after unroll
            const int t    = (r == 0) ? tc.x : tc.y;
            float m = x[base];
#pragma unroll
            for (int j = 1; j < kC; ++j) m = fmaxf(m, x[base + j]);
            float s  = 0.f;
            float xt = 0.f;                   // select-extract: keep x[] in regs
#pragma unroll
            for (int j = 0; j < kC; ++j) {
                s += __expf(x[base + j] - m);
                xt = (j == t) ? x[base + j] : xt;
            }
            const float ce = m + __logf(s) - xt;
            s_wce += ew[t] * ce;              // L1-hit gather, 14-entry table
        }

        // ---- L1 over matched rows ----
        const float d0 = fabsf(a0.x - b0.x) + fabsf(a0.y - b0.y) + fabsf(a1.x - b1.x);
        const float d1 = fabsf(a1.y - b1.y) + fabsf(a2.x - b2.x) + fabsf(a2.y - b2.y);
        const bool m0 = (tc.x != kNoObj);
        const bool m1 = (tc.y != kNoObj);
        s_abs += (m0 ? d0 : 0.f) + (m1 ? d1 : 0.f);
        cnt   += (m0 ? 1u : 0u) + (m1 ? 1u : 0u);
    }

    // ---- wave64 butterfly reduce ----
#pragma unroll
    for (int o = 32; o > 0; o >>= 1) {
        s_wce += __shfl_down(s_wce, o);
        s_abs += __shfl_down(s_abs, o);
        cnt   += __shfl_down(cnt, o);
    }
    __shared__ float        sw[kBlock / 64];
    __shared__ float        sa[kBlock / 64];
    __shared__ unsigned int sc[kBlock / 64];
    const int lane = threadIdx.x & 63;
    const int wid  = threadIdx.x >> 6;
    if (lane == 0) { sw[wid] = s_wce; sa[wid] = s_abs; sc[wid] = cnt; }
    __syncthreads();
    if (threadIdx.x == 0) {
        float        tw = 0.f;
        float        ta = 0.f;
        unsigned int tn = 0u;
#pragma unroll
        for (int i = 0; i < kBlock / 64; ++i) { tw += sw[i]; ta += sa[i]; tn += sc[i]; }
        atomicAdd(&ws->s_wce, (double)tw);
        atomicAdd(&ws->s_abs, (double)ta);
        atomicAdd(&ws->cnt,   (unsigned long long)tn);
    }
}

__global__ void finalize(const Accum* __restrict__ ws, float* __restrict__ out, int nrows) {
    if (threadIdx.x == 0 && blockIdx.x == 0) {
        const double lc = ws->s_wce / (double)nrows;
        const double n  = (double)ws->cnt * 3.0;
        const double ld = (ws->cnt > 0ull) ? (ws->s_abs / n) : 0.0;
        out[0] = (float)(kWClass * lc + kWDoa * ld);
    }
}

extern "C" void kernel_launch(void* const* d_in, const int* in_sizes, int n_in,
                              void* d_out, int out_size, void* d_ws, size_t ws_size,
                              hipStream_t stream) {
    const float* logits = (const float*)d_in[0];
    const float* pdoa   = (const float*)d_in[1];
    const float* tdoa   = (const float*)d_in[2];
    const float* ew     = (const float*)d_in[3];
    const int*   tcls   = (const int*)d_in[4];
    float*       out    = (float*)d_out;
    Accum*       ws     = (Accum*)d_ws;

    const int nrows  = in_sizes[4];      // B*T*N = 1,600,000 (even)
    const int npairs = nrows / 2;

    init_accum<<<1, 64, 0, stream>>>(ws);

    int grid = (npairs + kBlock - 1) / kBlock;
    if (grid > kMaxGrid) grid = kMaxGrid;
    loss_main<<<grid, kBlock, 0, stream>>>(logits, pdoa, tdoa, ew, tcls, npairs, ws);

    finalize<<<1, 64, 0, stream>>>(ws, out, nrows);
}

// Round 2
// 173.262 us; speedup vs baseline: 1.2779x; 1.2779x over previous
//
#include <hip/hip_runtime.h>

// SetCriterion loss (DETR-style) — fused reduction, v2.
//   v1 post-mortem: 95us/dispatch, constant across warm runs (L3-resident),
//   VALUBusy 6.4% -> stall-bound. Suspects: same-address fp64 atomics (2048
//   blocks x 3) and 112B-stride logit loads (64 lines/wave-instr).
//   v2: LDS-staged coalesced logit loads + per-block partials in d_ws
//   (no atomics) + separate 2048-way reduce kernel.
//
// Inputs (float32 unless noted):
//   d_in[0] pred_logits    [B,T,N,14]  -> 1,600,000 rows x 14
//   d_in[1] pred_doa       [B,T,N,3]
//   d_in[2] target_doa     [B*T,N,3]
//   d_in[3] empty_weight   [14]
//   d_in[4] target_classes int32 [B*T,N]
// Output: scalar float32.

constexpr int   kC        = 14;    // NUM_CLASSES + 1
constexpr int   kNoObj    = 13;
constexpr float kWDoa     = 2.0f;
constexpr int   kBlock    = 256;
constexpr int   kGrid     = 2048;  // fixed: every block writes its partial slot
constexpr int   kRowsTile = 256;   // rows staged per tile (1 row/thread)
constexpr int   kF4Tile   = kRowsTile * kC / 4;  // 896 float4 per tile

__global__ __launch_bounds__(kBlock) void loss_main(
    const float* __restrict__ logits,   // [R,14]
    const float* __restrict__ pdoa,     // [R,3]
    const float* __restrict__ tdoa,     // [R,3]
    const float* __restrict__ ew,       // [14]
    const int*   __restrict__ tcls,     // [R]
    int nrows,
    float* __restrict__ part_wce,       // [kGrid]
    float* __restrict__ part_abs,       // [kGrid]
    unsigned int* __restrict__ part_cnt)// [kGrid]
{
    __shared__ float lx[kRowsTile * kC];          // 14336 B
    __shared__ float        rw[kBlock / 64];
    __shared__ float        ra[kBlock / 64];
    __shared__ unsigned int rc[kBlock / 64];

    const int t = threadIdx.x;
    float        s_wce = 0.f;
    float        s_abs = 0.f;
    unsigned int cnt   = 0u;

    const int ntiles = nrows / kRowsTile;         // 6250 for the given shape
    for (int tile = blockIdx.x; tile < ntiles; tile += gridDim.x) {
        // ---- coalesced stage: 896 float4 = 28 KB, lane-contiguous ----
        const float4* src = reinterpret_cast<const float4*>(logits) + (size_t)tile * kF4Tile;
        float4*       dst = reinterpret_cast<float4*>(lx);
        dst[t]       = src[t];
        dst[t + 256] = src[t + 256];
        dst[t + 512] = src[t + 512];
        if (t < kF4Tile - 768) dst[t + 768] = src[t + 768];
        __syncthreads();

        // ---- this thread's row ----
        const int r  = tile * kRowsTile + t;
        const int tc = tcls[r];                   // coalesced int load
        float x[kC];
#pragma unroll
        for (int j = 0; j < kC; ++j) x[j] = lx[t * kC + j];  // 4-way alias max

        float m = x[0];
#pragma unroll
        for (int j = 1; j < kC; ++j) m = fmaxf(m, x[j]);
        float s  = 0.f;
        float xt = 0.f;                           // static-index extract (regs)
#pragma unroll
        for (int j = 0; j < kC; ++j) {
            s += __expf(x[j] - m);
            xt = (j == tc) ? x[j] : xt;
        }
        s_wce += ew[tc] * (m + __logf(s) - xt);   // 56B table, L1-resident

        // ---- DOA L1 (12B stride scalar loads, ~5 lanes/line) ----
        const float* pp = pdoa + (size_t)r * 3;
        const float* tp = tdoa + (size_t)r * 3;
        const float d = fabsf(pp[0] - tp[0]) + fabsf(pp[1] - tp[1]) + fabsf(pp[2] - tp[2]);
        if (tc != kNoObj) { s_abs += d; cnt += 1u; }

        __syncthreads();                          // lx reused next tile
    }

    // ---- wave64 butterfly + cross-wave, one partial per block ----
#pragma unroll
    for (int o = 32; o > 0; o >>= 1) {
        s_wce += __shfl_down(s_wce, o);
        s_abs += __shfl_down(s_abs, o);
        cnt   += __shfl_down(cnt, o);
    }
    const int lane = t & 63, wid = t >> 6;
    if (lane == 0) { rw[wid] = s_wce; ra[wid] = s_abs; rc[wid] = cnt; }
    __syncthreads();
    if (t == 0) {
        float tw = 0.f, ta = 0.f; unsigned int tn = 0u;
#pragma unroll
        for (int i = 0; i < kBlock / 64; ++i) { tw += rw[i]; ta += ra[i]; tn += rc[i]; }
        part_wce[blockIdx.x] = tw;               // plain stores, no atomics
        part_abs[blockIdx.x] = ta;
        part_cnt[blockIdx.x] = tn;
    }
}

__global__ __launch_bounds__(kBlock) void finalize(
    const float* __restrict__ part_wce,
    const float* __restrict__ part_abs,
    const unsigned int* __restrict__ part_cnt,
    float* __restrict__ out, int nrows, int nparts)
{
    double w = 0.0, a = 0.0;
    unsigned long long c = 0ull;
    for (int i = threadIdx.x; i < nparts; i += kBlock) {
        w += (double)part_wce[i];
        a += (double)part_abs[i];
        c += (unsigned long long)part_cnt[i];
    }
#pragma unroll
    for (int o = 32; o > 0; o >>= 1) {
        w += __shfl_down(w, o);
        a += __shfl_down(a, o);
        c += __shfl_down(c, o);
    }
    __shared__ double sw[kBlock / 64], sa[kBlock / 64];
    __shared__ unsigned long long sc[kBlock / 64];
    const int lane = threadIdx.x & 63, wid = threadIdx.x >> 6;
    if (lane == 0) { sw[wid] = w; sa[wid] = a; sc[wid] = c; }
    __syncthreads();
    if (threadIdx.x == 0) {
        double tw = 0.0, ta = 0.0;
        unsigned long long tc = 0ull;
#pragma unroll
        for (int i = 0; i < kBlock / 64; ++i) { tw += sw[i]; ta += sa[i]; tc += sc[i]; }
        const double lc = tw / (double)nrows;
        const double ld = (tc > 0ull) ? (ta / (3.0 * (double)tc)) : 0.0;
        out[0] = (float)(lc + (double)kWDoa * ld);
    }
}

extern "C" void kernel_launch(void* const* d_in, const int* in_sizes, int n_in,
                              void* d_out, int out_size, void* d_ws, size_t ws_size,
                              hipStream_t stream) {
    const float* logits = (const float*)d_in[0];
    const float* pdoa   = (const float*)d_in[1];
    const float* tdoa   = (const float*)d_in[2];
    const float* ew     = (const float*)d_in[3];
    const int*   tcls   = (const int*)d_in[4];
    float*       out    = (float*)d_out;

    float*        pw = (float*)d_ws;
    float*        pa = pw + kGrid;
    unsigned int* pc = (unsigned int*)(pa + kGrid);

    const int nrows = in_sizes[4];   // B*T*N = 1,600,000 (multiple of 256)

    loss_main<<<kGrid, kBlock, 0, stream>>>(logits, pdoa, tdoa, ew, tcls, nrows,
                                            pw, pa, pc);
    finalize<<<1, kBlock, 0, stream>>>(pw, pa, pc, out, nrows, kGrid);
}

// Round 3
// 172.405 us; speedup vs baseline: 1.2843x; 1.0050x over previous
//
#include <hip/hip_runtime.h>

// SetCriterion loss (DETR-style) — fused reduction, v3.
//   v2 post-mortem: loss_main ~47us (out of top-5), atomics removal + logit
//   coalescing worked. Remaining losses: (a) 6250 tiles over 2048 blocks ->
//   106 blocks do 4 tiles vs 3 (x1.31 makespan), (b) DOA/tcls scalar loads
//   at 12B stride (~12 lines/wave-instr).
//   v3: kGrid=1250 -> exactly 5 tiles/block (balanced); stage pdoa/tdoa/tcls
//   through LDS with lane-contiguous float4 so ALL global traffic is
//   coalesced. LDS-read aliasing: stride-14 rows = 4-way (1.58x, ~2us),
//   stride-3 / stride-1 = 2-way = free.
//
// Inputs (float32 unless noted):
//   d_in[0] pred_logits    [1.6M rows, 14]
//   d_in[1] pred_doa       [1.6M rows, 3]
//   d_in[2] target_doa     [1.6M rows, 3]
//   d_in[3] empty_weight   [14]
//   d_in[4] target_classes int32 [1.6M]
// Output: scalar float32.

constexpr int   kC     = 14;     // NUM_CLASSES + 1
constexpr int   kNoObj = 13;
constexpr float kWDoa  = 2.0f;
constexpr int   kBlock = 256;
constexpr int   kGrid  = 1250;   // 6250 tiles / 5 per block, exact
constexpr int   kRows  = 256;    // rows per tile (1 row/thread)
constexpr int   kF4Log = kRows * kC / 4;  // 896 float4
constexpr int   kF4Doa = kRows * 3 / 4;   // 192 float4

__global__ __launch_bounds__(kBlock) void loss_main(
    const float* __restrict__ logits,   // [R,14]
    const float* __restrict__ pdoa,     // [R,3]
    const float* __restrict__ tdoa,     // [R,3]
    const float* __restrict__ ew,       // [14]
    const int*   __restrict__ tcls,     // [R]
    int nrows,
    float* __restrict__ part_wce,       // [kGrid]
    float* __restrict__ part_abs,       // [kGrid]
    unsigned int* __restrict__ part_cnt)// [kGrid]
{
    __shared__ float lx [kRows * kC];   // 14336 B
    __shared__ float lpd[kRows * 3];    //  3072 B
    __shared__ float ltd[kRows * 3];    //  3072 B
    __shared__ int   lcl[kRows];        //  1024 B
    __shared__ float        rw[kBlock / 64];
    __shared__ float        ra[kBlock / 64];
    __shared__ unsigned int rc[kBlock / 64];

    const int t = threadIdx.x;
    float        s_wce = 0.f;
    float        s_abs = 0.f;
    unsigned int cnt   = 0u;

    const int ntiles = nrows / kRows;   // 6250
    for (int tile = blockIdx.x; tile < ntiles; tile += kGrid) {
        // ---- stage everything with lane-contiguous float4 ----
        const float4* ls = reinterpret_cast<const float4*>(logits) + (size_t)tile * kF4Log;
        float4*       ld = reinterpret_cast<float4*>(lx);
        ld[t]       = ls[t];
        ld[t + 256] = ls[t + 256];
        ld[t + 512] = ls[t + 512];
        if (t < kF4Log - 768) ld[t + 768] = ls[t + 768];   // t < 128

        const float4* ps = reinterpret_cast<const float4*>(pdoa) + (size_t)tile * kF4Doa;
        const float4* ts = reinterpret_cast<const float4*>(tdoa) + (size_t)tile * kF4Doa;
        if (t < kF4Doa) {
            reinterpret_cast<float4*>(lpd)[t] = ps[t];
            reinterpret_cast<float4*>(ltd)[t] = ts[t];
        }
        lcl[t] = tcls[(size_t)tile * kRows + t];
        __syncthreads();

        // ---- this thread's row ----
        const int tc = lcl[t];
        float x[kC];
#pragma unroll
        for (int j = 0; j < kC; ++j) x[j] = lx[t * kC + j];

        float m = x[0];
#pragma unroll
        for (int j = 1; j < kC; ++j) m = fmaxf(m, x[j]);
        float s  = 0.f;
        float xt = 0.f;                     // static-index extract (regs)
#pragma unroll
        for (int j = 0; j < kC; ++j) {
            s += __expf(x[j] - m);
            xt = (j == tc) ? x[j] : xt;
        }
        s_wce += ew[tc] * (m + __logf(s) - xt);   // 56B table, L1-resident

        const float d = fabsf(lpd[3 * t + 0] - ltd[3 * t + 0])
                      + fabsf(lpd[3 * t + 1] - ltd[3 * t + 1])
                      + fabsf(lpd[3 * t + 2] - ltd[3 * t + 2]);
        if (tc != kNoObj) { s_abs += d; cnt += 1u; }

        __syncthreads();                    // LDS reused next tile
    }

    // ---- wave64 butterfly + cross-wave, one partial per block ----
#pragma unroll
    for (int o = 32; o > 0; o >>= 1) {
        s_wce += __shfl_down(s_wce, o);
        s_abs += __shfl_down(s_abs, o);
        cnt   += __shfl_down(cnt, o);
    }
    const int lane = t & 63, wid = t >> 6;
    if (lane == 0) { rw[wid] = s_wce; ra[wid] = s_abs; rc[wid] = cnt; }
    __syncthreads();
    if (t == 0) {
        float tw = 0.f, ta = 0.f; unsigned int tn = 0u;
#pragma unroll
        for (int i = 0; i < kBlock / 64; ++i) { tw += rw[i]; ta += ra[i]; tn += rc[i]; }
        part_wce[blockIdx.x] = tw;          // plain stores, no atomics
        part_abs[blockIdx.x] = ta;
        part_cnt[blockIdx.x] = tn;
    }
}

__global__ __launch_bounds__(kBlock) void finalize(
    const float* __restrict__ part_wce,
    const float* __restrict__ part_abs,
    const unsigned int* __restrict__ part_cnt,
    float* __restrict__ out, int nrows, int nparts)
{
    double w = 0.0, a = 0.0;
    unsigned long long c = 0ull;
    for (int i = threadIdx.x; i < nparts; i += kBlock) {
        w += (double)part_wce[i];
        a += (double)part_abs[i];
        c += (unsigned long long)part_cnt[i];
    }
#pragma unroll
    for (int o = 32; o > 0; o >>= 1) {
        w += __shfl_down(w, o);
        a += __shfl_down(a, o);
        c += __shfl_down(c, o);
    }
    __shared__ double sw[kBlock / 64], sa[kBlock / 64];
    __shared__ unsigned long long sc[kBlock / 64];
    const int lane = threadIdx.x & 63, wid = threadIdx.x >> 6;
    if (lane == 0) { sw[wid] = w; sa[wid] = a; sc[wid] = c; }
    __syncthreads();
    if (threadIdx.x == 0) {
        double tw = 0.0, ta = 0.0;
        unsigned long long tc = 0ull;
#pragma unroll
        for (int i = 0; i < kBlock / 64; ++i) { tw += sw[i]; ta += sa[i]; tc += sc[i]; }
        const double lc = tw / (double)nrows;
        const double ld = (tc > 0ull) ? (ta / (3.0 * (double)tc)) : 0.0;
        out[0] = (float)(lc + (double)kWDoa * ld);
    }
}

extern "C" void kernel_launch(void* const* d_in, const int* in_sizes, int n_in,
                              void* d_out, int out_size, void* d_ws, size_t ws_size,
                              hipStream_t stream) {
    const float* logits = (const float*)d_in[0];
    const float* pdoa   = (const float*)d_in[1];
    const float* tdoa   = (const float*)d_in[2];
    const float* ew     = (const float*)d_in[3];
    const int*   tcls   = (const int*)d_in[4];
    float*       out    = (float*)d_out;

    float*        pw = (float*)d_ws;
    float*        pa = pw + kGrid;
    unsigned int* pc = (unsigned int*)(pa + kGrid);

    const int nrows = in_sizes[4];   // 1,600,000 = 6250 * 256

    loss_main<<<kGrid, kBlock, 0, stream>>>(logits, pdoa, tdoa, ew, tcls, nrows,
                                            pw, pa, pc);
    finalize<<<1, kBlock, 0, stream>>>(pw, pa, pc, out, nrows, kGrid);
}